// Round 35
// baseline (72.784 us; speedup 1.0000x reference)
//
#include <hip/hip_runtime.h>

typedef __attribute__((ext_vector_type(8))) short bf16x8;
typedef __attribute__((ext_vector_type(4))) float f32x4;

#define HID 64
#define IN_DIM 128
// binC (float values): 128 KB LDS window
#define WINB 15                   // 32768 nodes per block window
#define WIN (1 << WINB)
#define NGC 4                     // ceil(100000 / 32768) window groups
#define MCH 64                    // edge chunks -> 256 blocks = 1/CU
#define SCAN_TPB 1024             // binC: 16 waves/block
// binA (packed u8 counters, single 128 KB window covering all N) — fused into K1
#define AWORDS 32768              // u32 words: 131072 u8 counters >= N
#define MCH2 64                   // binA chunk blocks (256 threads each, fused grid)
// dense
#define DNODES 64

__device__ __forceinline__ unsigned short f2bf(float f) {   // RTN f32->bf16
    unsigned u = __builtin_bit_cast(unsigned, f);
    return (unsigned short)((u + 0x7FFFu + ((u >> 16) & 1u)) >> 16);
}

// ---- K0: prep Wt[j][k] = bf16(W_in[k][j])  (must precede K1: dense reads Wt) ----
__global__ __launch_bounds__(256) void k_prep(const float* __restrict__ W_in,
                                              unsigned short* __restrict__ Wt) {
    int i = blockIdx.x * 256 + threadIdx.x;
    if (i < IN_DIM * HID) Wt[i] = f2bf(W_in[(i & 127) * HID + (i >> 7)]);
}

// ---- K1: fused {binA | dense-z}. binA blocks first (dispatch early, overlap with
// dense); NO cross-block data flow inside K1 (Wt prepped in K0; z/partA consumed in K2).
__global__ __launch_bounds__(256) void k_fused(const float* __restrict__ x,
                                               const int* __restrict__ dst,
                                               const float* __restrict__ b_in,
                                               const float* __restrict__ W_g,
                                               const float* __restrict__ W_out,
                                               const unsigned short* __restrict__ Wt,
                                               unsigned* __restrict__ partA,
                                               float* __restrict__ z,
                                               int N, int E, int chunkA) {
    const int t = threadIdx.x;

    if ((int)blockIdx.x < MCH2) {
        // ---- binA: u8-packed degree count, single 128 KB window ----
        __shared__ unsigned cnt[AWORDS];   // 128 KB
        for (int i = t; i < AWORDS; i += 256) cnt[i] = 0;
        __syncthreads();

        const int e0 = blockIdx.x * chunkA;
        const int e1 = min(E, e0 + chunkA);
        for (int e = e0 + t * 4; e + 3 < e1; e += 256 * 4) {
            int4 d4 = *(const int4*)(dst + e);
            atomicAdd(&cnt[(unsigned)d4.x >> 2], 1u << (((unsigned)d4.x & 3u) << 3));
            atomicAdd(&cnt[(unsigned)d4.y >> 2], 1u << (((unsigned)d4.y & 3u) << 3));
            atomicAdd(&cnt[(unsigned)d4.z >> 2], 1u << (((unsigned)d4.z & 3u) << 3));
            atomicAdd(&cnt[(unsigned)d4.w >> 2], 1u << (((unsigned)d4.w & 3u) << 3));
        }
        __syncthreads();

        unsigned* outp = partA + (size_t)blockIdx.x * AWORDS;
        for (int i = t; i < AWORDS; i += 256) outp[i] = cnt[i];
        return;
    }

    // ---- dense: MFMA, A-frags from global, B-frags in-loop from L1-hot Wt ----
    __shared__ float weff_l[HID];
    __shared__ float bl[HID];
    __shared__ float zp[DNODES];

    const int row0 = (blockIdx.x - MCH2) * DNODES;

    {   // weff = W_g @ W_out + bias stage
        const float* wg = W_g + (t >> 2) * HID + (t & 3) * 16;
        const float* wo = W_out + (t & 3) * 16;
        float s = 0.0f;
#pragma unroll
        for (int p = 0; p < 16; ++p) s = fmaf(wg[p], wo[p], s);
        s += __shfl_xor(s, 1, 64);
        s += __shfl_xor(s, 2, 64);
        if ((t & 3) == 0) weff_l[t >> 2] = s;
        if (t < HID) bl[t] = b_in[t];
    }

    const int w    = __builtin_amdgcn_readfirstlane(t >> 6);  // wave id (SGPR)
    const int lane = t & 63;

    f32x4 acc[4] = {{0,0,0,0},{0,0,0,0},{0,0,0,0},{0,0,0,0}};
    {
        int grow = row0 + w * 16 + (lane & 15);
        if (grow >= N) grow = N - 1;
        const float* xr = x + (size_t)grow * IN_DIM + (lane >> 4) * 8;
        const unsigned short* wtb = Wt + (size_t)(lane & 15) * IN_DIM + (lane >> 4) * 8;
#pragma unroll
        for (int kk = 0; kk < 4; ++kk) {
            float4 a0 = *(const float4*)(xr + kk * 32);
            float4 a1 = *(const float4*)(xr + kk * 32 + 4);
            bf16x8 af;
            af[0] = (short)f2bf(a0.x); af[1] = (short)f2bf(a0.y);
            af[2] = (short)f2bf(a0.z); af[3] = (short)f2bf(a0.w);
            af[4] = (short)f2bf(a1.x); af[5] = (short)f2bf(a1.y);
            af[6] = (short)f2bf(a1.z); af[7] = (short)f2bf(a1.w);
#pragma unroll
            for (int nf = 0; nf < 4; ++nf) {
                bf16x8 bf = *(const bf16x8*)(wtb + (size_t)(nf * 16) * IN_DIM + kk * 32);
                acc[nf] = __builtin_amdgcn_mfma_f32_16x16x32_bf16(af, bf, acc[nf], 0, 0, 0);
            }
        }
    }
    __syncthreads();   // weff_l/bl ready

    {   // epilogue: z[row] = sum_col relu(h + b) * weff
        float p[4] = {0.f, 0.f, 0.f, 0.f};
#pragma unroll
        for (int nf = 0; nf < 4; ++nf) {
            const int col = nf * 16 + (lane & 15);
            const float bc = bl[col], wc = weff_l[col];
#pragma unroll
            for (int r = 0; r < 4; ++r)
                p[r] = fmaf(fmaxf(acc[nf][r] + bc, 0.0f), wc, p[r]);
        }
#pragma unroll
        for (int r = 0; r < 4; ++r) {
            p[r] += __shfl_xor(p[r], 1, 64);
            p[r] += __shfl_xor(p[r], 2, 64);
            p[r] += __shfl_xor(p[r], 4, 64);
            p[r] += __shfl_xor(p[r], 8, 64);
        }
        if ((lane & 15) == 0) {
#pragma unroll
            for (int r = 0; r < 4; ++r)
                zp[w * 16 + (lane >> 4) * 4 + r] = p[r];   // C row = (lane>>4)*4 + r
        }
    }
    __syncthreads();

    if (t < 64) {
        int n = row0 + t; if (n >= N) n = N - 1;
        z[n] = zp[t];
    }
}

// ---- K2: dinv + zs, quad-per-thread (u32 word IS the 4-node u8 quad; coalesced) ----
__global__ __launch_bounds__(256) void k_dinvz(const unsigned* __restrict__ partA,
                                               const float* __restrict__ z,
                                               float* __restrict__ dinv,
                                               float* __restrict__ zs, int N) {
    int i4 = (blockIdx.x * blockDim.x + threadIdx.x) * 4;
    if (i4 >= N) return;                   // N % 4 == 0
    const unsigned* base = partA + (i4 >> 2);
    int d0 = 0, d1 = 0, d2 = 0, d3 = 0;
#pragma unroll 8
    for (int m = 0; m < MCH2; ++m) {
        unsigned w = base[(size_t)m * AWORDS];
        d0 += (int)(w & 0xFFu);
        d1 += (int)((w >> 8) & 0xFFu);
        d2 += (int)((w >> 16) & 0xFFu);
        d3 += (int)((w >> 24) & 0xFFu);
    }
    float4 dv;
    dv.x = rsqrtf((float)d0 + 1.0f); dv.y = rsqrtf((float)d1 + 1.0f);
    dv.z = rsqrtf((float)d2 + 1.0f); dv.w = rsqrtf((float)d3 + 1.0f);
    float4 zv = *(const float4*)(z + i4);
    float4 s;
    s.x = zv.x * dv.x; s.y = zv.y * dv.y; s.z = zv.z * dv.z; s.w = zv.w * dv.w;
    *(float4*)(dinv + i4) = dv;
    *(float4*)(zs + i4) = s;
}

// ---- K3: binned value scatter, 128 KB LDS window, 1024-thread blocks ----
__global__ __launch_bounds__(SCAN_TPB) void k_binC(const int* __restrict__ eidx,
                                                   const float* __restrict__ zs,
                                                   float* __restrict__ partf,
                                                   int E, int chunk) {
    __shared__ float acc[WIN];             // 128 KB: covers 32768 nodes
    for (int i = threadIdx.x; i < WIN; i += SCAN_TPB) acc[i] = 0.0f;
    __syncthreads();

    const int g = blockIdx.x % NGC;
    const int lo = g << WINB;
    const int e0 = (blockIdx.x / NGC) * chunk;
    const int e1 = min(E, e0 + chunk);
    for (int e = e0 + (int)threadIdx.x * 4; e + 3 < e1; e += SCAN_TPB * 4) {
        int4 s4 = *(const int4*)(eidx + e);        // src
        int4 d4 = *(const int4*)(eidx + E + e);    // dst (both loads in flight)
        unsigned v;
        v = (unsigned)(d4.x - lo); if (v < WIN) atomicAdd(&acc[v], zs[s4.x]);
        v = (unsigned)(d4.y - lo); if (v < WIN) atomicAdd(&acc[v], zs[s4.y]);
        v = (unsigned)(d4.z - lo); if (v < WIN) atomicAdd(&acc[v], zs[s4.z]);
        v = (unsigned)(d4.w - lo); if (v < WIN) atomicAdd(&acc[v], zs[s4.w]);
    }
    __syncthreads();

    float* outp = partf + (size_t)blockIdx.x * WIN;
    for (int i = threadIdx.x; i < WIN; i += SCAN_TPB) outp[i] = acc[i];
}

// ---- K4: final (4 nodes/thread, float4): out = dinv*(sum partials + zs) + c ----
__global__ __launch_bounds__(256) void k_redFinal(const float* __restrict__ partf,
                                                  const float* __restrict__ dinv,
                                                  const float* __restrict__ zs,
                                                  const float* __restrict__ b_g,
                                                  const float* __restrict__ W_out,
                                                  const float* __restrict__ b_out,
                                                  float* __restrict__ out, int N) {
    const int lane = threadIdx.x & 63;
    float c = b_g[lane] * W_out[lane];
#pragma unroll
    for (int off = 32; off > 0; off >>= 1)
        c += __shfl_xor(c, off, 64);
    c += b_out[0];

    int i4 = (blockIdx.x * blockDim.x + threadIdx.x) * 4;
    if (i4 >= N) return;                   // N % 4 == 0
    const int g = i4 >> WINB, idx = i4 & (WIN - 1);   // all 4 nodes in same window

    float4 a = *(const float4*)(zs + i4);  // self-loop
#pragma unroll 8
    for (int m = 0; m < MCH; ++m) {
        float4 p = *(const float4*)(partf + (((size_t)m * NGC + g) << WINB) + idx);
        a.x += p.x; a.y += p.y; a.z += p.z; a.w += p.w;
    }
    float4 dv = *(const float4*)(dinv + i4);
    float4 o;
    o.x = fmaf(dv.x, a.x, c); o.y = fmaf(dv.y, a.y, c);
    o.z = fmaf(dv.z, a.z, c); o.w = fmaf(dv.w, a.w, c);
    *(float4*)(out + i4) = o;
}

// ---------------- launch ----------------

extern "C" void kernel_launch(void* const* d_in, const int* in_sizes, int n_in,
                              void* d_out, int out_size, void* d_ws, size_t ws_size,
                              hipStream_t stream) {
    const float* x     = (const float*)d_in[0];
    const int*   eidx  = (const int*)d_in[1];
    const float* W_in  = (const float*)d_in[2];
    const float* b_in  = (const float*)d_in[3];
    const float* W_g   = (const float*)d_in[4];
    const float* b_g   = (const float*)d_in[5];
    const float* W_out = (const float*)d_in[6];
    const float* b_out = (const float*)d_in[7];
    float* out = (float*)d_out;

    const int N = in_sizes[0] / IN_DIM;   // 100000 (divisible by 4)
    const int E = in_sizes[1] / 2;        // 1600000

    // chunks: multiples of 4
    const int chunk  = (((E + MCH  - 1) / MCH ) + 3) & ~3;
    const int chunkA = (((E + MCH2 - 1) / MCH2) + 3) & ~3;

    // ws layout: region0 = max(partf 33.6MB, partA 8.4MB) | z[N] | dinv[N] | zs[N] | Wt
    const size_t partElems0 = (size_t)NGC * MCH * WIN;      // binC floats
    const size_t partElemsA = (size_t)MCH2 * AWORDS;        // binA u32 words
    const size_t partElems = partElems0 > partElemsA ? partElems0 : partElemsA;
    unsigned* partA = (unsigned*)d_ws;    // consumed by k_dinvz before binC overwrites
    float*    partf = (float*)d_ws;
    float*    z     = (float*)d_ws + partElems;
    float*    dinv  = z + N;
    float*    zs    = dinv + N;
    unsigned short* Wt = (unsigned short*)(zs + N);

    const int nG = (N + DNODES - 1) / DNODES;   // 1563 dense blocks
    k_prep<<<(IN_DIM * HID + 255) / 256, 256, 0, stream>>>(W_in, Wt);
    k_fused<<<MCH2 + nG, 256, 0, stream>>>(x, eidx + E, b_in, W_g, W_out, Wt,
                                           partA, z, N, E, chunkA);
    k_dinvz<<<((N + 3) / 4 + 255) / 256, 256, 0, stream>>>(partA, z, dinv, zs, N);
    k_binC<<<NGC * MCH, SCAN_TPB, 0, stream>>>(eidx, zs, partf, E, chunk);
    k_redFinal<<<((N + 3) / 4 + 255) / 256, 256, 0, stream>>>(partf, dinv, zs, b_g, W_out, b_out, out, N);
}

// Round 36
// 65.447 us; speedup vs baseline: 1.1121x; 1.1121x over previous
//
#include <hip/hip_runtime.h>

typedef __attribute__((ext_vector_type(8))) short bf16x8;
typedef __attribute__((ext_vector_type(4))) float f32x4;

#define HID 64
#define IN_DIM 128
// binC (float values): 128 KB LDS window
#define WINB 15                   // 32768 nodes per block window
#define WIN (1 << WINB)
#define NGC 4                     // ceil(100000 / 32768) window groups
#define MCH 64                    // edge chunks -> 256 blocks = 1/CU
#define SCAN_TPB 1024             // 16 waves/block -> 16 waves/CU at 1 block/CU
// binA (packed u8 counters, single 128 KB window covering all N)
#define AWORDS 32768              // u32 words: 131072 u8 counters >= N
#define MCH2 64                   // chunk blocks
#define PREP_BLOCKS 8             // prep blocks appended to binA grid (8 x 1024)
// dense
#define DNODES 64

__device__ __forceinline__ unsigned short f2bf(float f) {   // RTN f32->bf16
    unsigned u = __builtin_bit_cast(unsigned, f);
    return (unsigned short)((u + 0x7FFFu + ((u >> 16) & 1u)) >> 16);
}

// ------- binA (+prep): u8-packed degree count, single window; last 8 blocks build Wt -------
__global__ __launch_bounds__(SCAN_TPB) void k_binA(const int* __restrict__ dst,
                                                   unsigned* __restrict__ partA,
                                                   const float* __restrict__ W_in,
                                                   unsigned short* __restrict__ Wt,
                                                   int E, int chunkA) {
    if ((int)blockIdx.x >= MCH2) {
        // prep: Wt[j][k] = bf16(W_in[k][j])
        int i = (blockIdx.x - MCH2) * SCAN_TPB + threadIdx.x;
        if (i < IN_DIM * HID) Wt[i] = f2bf(W_in[(i & 127) * HID + (i >> 7)]);
        return;
    }

    __shared__ unsigned cnt[AWORDS];       // 128 KB, 4 nodes per word (u8 counters)
    for (int i = threadIdx.x; i < AWORDS; i += SCAN_TPB) cnt[i] = 0;
    __syncthreads();

    const int e0 = blockIdx.x * chunkA;
    const int e1 = min(E, e0 + chunkA);
    for (int e = e0 + (int)threadIdx.x * 4; e + 3 < e1; e += SCAN_TPB * 4) {
        int4 d4 = *(const int4*)(dst + e);
        atomicAdd(&cnt[(unsigned)d4.x >> 2], 1u << (((unsigned)d4.x & 3u) << 3));
        atomicAdd(&cnt[(unsigned)d4.y >> 2], 1u << (((unsigned)d4.y & 3u) << 3));
        atomicAdd(&cnt[(unsigned)d4.z >> 2], 1u << (((unsigned)d4.z & 3u) << 3));
        atomicAdd(&cnt[(unsigned)d4.w >> 2], 1u << (((unsigned)d4.w & 3u) << 3));
    }
    __syncthreads();

    unsigned* outp = partA + (size_t)blockIdx.x * AWORDS;
    for (int i = threadIdx.x; i < AWORDS; i += SCAN_TPB) outp[i] = cnt[i];
}

// -------- dense: MFMA, A-frags from global, B-frags in-loop from L1-hot Wt --------
__global__ __launch_bounds__(256) void k_dense(const float* __restrict__ x,
                                               const unsigned short* __restrict__ Wt,
                                               const float* __restrict__ b_in,
                                               const float* __restrict__ W_g,
                                               const float* __restrict__ W_out,
                                               const unsigned* __restrict__ partA,
                                               float* __restrict__ dinv,
                                               float* __restrict__ zs,
                                               int N) {
    __shared__ float weff_l[HID];
    __shared__ float bl[HID];
    __shared__ float zp[DNODES];
    __shared__ int   tailp[4][DNODES];

    const int t = threadIdx.x;
    const int row0 = blockIdx.x * DNODES;

    // ---- hoisted tail loads: 16 partA words/thread (u8 lanes), issued first ----
    unsigned tw[16];
    int tail_sh;
    {
        const int tn = t & 63;
        const int tq = t >> 6;
        int n = row0 + tn; if (n >= N) n = N - 1;
        tail_sh = (n & 3) << 3;
        const unsigned* base = partA + (n >> 2);
#pragma unroll
        for (int j = 0; j < 16; ++j)
            tw[j] = base[(size_t)(tq * 16 + j) * AWORDS];
    }

    // ---- weff = W_g @ W_out + bias stage ----
    {
        const float* wg = W_g + (t >> 2) * HID + (t & 3) * 16;
        const float* wo = W_out + (t & 3) * 16;
        float s = 0.0f;
#pragma unroll
        for (int p = 0; p < 16; ++p) s = fmaf(wg[p], wo[p], s);
        s += __shfl_xor(s, 1, 64);
        s += __shfl_xor(s, 2, 64);
        if ((t & 3) == 0) weff_l[t >> 2] = s;
        if (t < HID) bl[t] = b_in[t];
    }

    const int w    = __builtin_amdgcn_readfirstlane(t >> 6);  // wave id (SGPR)
    const int lane = t & 63;

    // ---- A direct from global + MFMA; B-frags loaded in-loop (L1-hot) ----
    f32x4 acc[4] = {{0,0,0,0},{0,0,0,0},{0,0,0,0},{0,0,0,0}};
    {
        int grow = row0 + w * 16 + (lane & 15);
        if (grow >= N) grow = N - 1;
        const float* xr = x + (size_t)grow * IN_DIM + (lane >> 4) * 8;
        const unsigned short* wtb = Wt + (size_t)(lane & 15) * IN_DIM + (lane >> 4) * 8;
#pragma unroll
        for (int kk = 0; kk < 4; ++kk) {
            float4 a0 = *(const float4*)(xr + kk * 32);
            float4 a1 = *(const float4*)(xr + kk * 32 + 4);
            bf16x8 af;
            af[0] = (short)f2bf(a0.x); af[1] = (short)f2bf(a0.y);
            af[2] = (short)f2bf(a0.z); af[3] = (short)f2bf(a0.w);
            af[4] = (short)f2bf(a1.x); af[5] = (short)f2bf(a1.y);
            af[6] = (short)f2bf(a1.z); af[7] = (short)f2bf(a1.w);
#pragma unroll
            for (int nf = 0; nf < 4; ++nf) {
                bf16x8 bf = *(const bf16x8*)(wtb + (size_t)(nf * 16) * IN_DIM + kk * 32);
                acc[nf] = __builtin_amdgcn_mfma_f32_16x16x32_bf16(af, bf, acc[nf], 0, 0, 0);
            }
        }
    }
    __syncthreads();   // weff_l/bl ready

    // ---- epilogue: z[row] = sum_col relu(h + b) * weff ----
    {
        float p[4] = {0.f, 0.f, 0.f, 0.f};
#pragma unroll
        for (int nf = 0; nf < 4; ++nf) {
            const int col = nf * 16 + (lane & 15);
            const float bc = bl[col], wc = weff_l[col];
#pragma unroll
            for (int r = 0; r < 4; ++r)
                p[r] = fmaf(fmaxf(acc[nf][r] + bc, 0.0f), wc, p[r]);
        }
#pragma unroll
        for (int r = 0; r < 4; ++r) {
            p[r] += __shfl_xor(p[r], 1, 64);
            p[r] += __shfl_xor(p[r], 2, 64);
            p[r] += __shfl_xor(p[r], 4, 64);
            p[r] += __shfl_xor(p[r], 8, 64);
        }
        if ((lane & 15) == 0) {
#pragma unroll
            for (int r = 0; r < 4; ++r)
                zp[w * 16 + (lane >> 4) * 4 + r] = p[r];   // C row = (lane>>4)*4 + r
        }
    }

    // ---- tail: sum the hoisted u8 lanes (already landed) ----
    {
        int d = 0;
#pragma unroll
        for (int j = 0; j < 16; ++j)
            d += (int)((tw[j] >> tail_sh) & 0xFFu);
        tailp[t >> 6][t & 63] = d;
    }
    __syncthreads();   // zp + tailp ready

    if (t < 64) {
        int n = row0 + t; if (n >= N) n = N - 1;
        int d = tailp[0][t] + tailp[1][t] + tailp[2][t] + tailp[3][t];
        float di = rsqrtf((float)d + 1.0f);
        dinv[n] = di;
        zs[n]   = zp[t] * di;
    }
}

// ---- pass C: binned value scatter, 128 KB LDS window, 1024-thread blocks ----
__global__ __launch_bounds__(SCAN_TPB) void k_binC(const int* __restrict__ eidx,
                                                   const float* __restrict__ zs,
                                                   float* __restrict__ partf,
                                                   int E, int chunk) {
    __shared__ float acc[WIN];             // 128 KB: covers 32768 nodes
    for (int i = threadIdx.x; i < WIN; i += SCAN_TPB) acc[i] = 0.0f;
    __syncthreads();

    const int g = blockIdx.x % NGC;
    const int lo = g << WINB;
    const int e0 = (blockIdx.x / NGC) * chunk;
    const int e1 = min(E, e0 + chunk);
    for (int e = e0 + (int)threadIdx.x * 4; e + 3 < e1; e += SCAN_TPB * 4) {
        int4 s4 = *(const int4*)(eidx + e);        // src
        int4 d4 = *(const int4*)(eidx + E + e);    // dst (both loads in flight)
        unsigned v;
        v = (unsigned)(d4.x - lo); if (v < WIN) atomicAdd(&acc[v], zs[s4.x]);
        v = (unsigned)(d4.y - lo); if (v < WIN) atomicAdd(&acc[v], zs[s4.y]);
        v = (unsigned)(d4.z - lo); if (v < WIN) atomicAdd(&acc[v], zs[s4.z]);
        v = (unsigned)(d4.w - lo); if (v < WIN) atomicAdd(&acc[v], zs[s4.w]);
    }
    __syncthreads();

    float* outp = partf + (size_t)blockIdx.x * WIN;
    for (int i = threadIdx.x; i < WIN; i += SCAN_TPB) outp[i] = acc[i];
}

// ------- final (4 nodes/thread, float4): out = dinv*(sum partials + zs) + c -------
__global__ __launch_bounds__(256) void k_redFinal(const float* __restrict__ partf,
                                                  const float* __restrict__ dinv,
                                                  const float* __restrict__ zs,
                                                  const float* __restrict__ b_g,
                                                  const float* __restrict__ W_out,
                                                  const float* __restrict__ b_out,
                                                  float* __restrict__ out, int N) {
    const int lane = threadIdx.x & 63;
    float c = b_g[lane] * W_out[lane];
#pragma unroll
    for (int off = 32; off > 0; off >>= 1)
        c += __shfl_xor(c, off, 64);
    c += b_out[0];

    int i4 = (blockIdx.x * blockDim.x + threadIdx.x) * 4;
    if (i4 >= N) return;                   // N % 4 == 0: full quads only
    const int g = i4 >> WINB, idx = i4 & (WIN - 1);   // all 4 nodes in same window

    float4 a = *(const float4*)(zs + i4);  // self-loop
#pragma unroll 8
    for (int m = 0; m < MCH; ++m) {
        float4 p = *(const float4*)(partf + (((size_t)m * NGC + g) << WINB) + idx);
        a.x += p.x; a.y += p.y; a.z += p.z; a.w += p.w;
    }
    float4 dv = *(const float4*)(dinv + i4);
    float4 o;
    o.x = fmaf(dv.x, a.x, c); o.y = fmaf(dv.y, a.y, c);
    o.z = fmaf(dv.z, a.z, c); o.w = fmaf(dv.w, a.w, c);
    *(float4*)(out + i4) = o;
}

// ---------------- launch ----------------

extern "C" void kernel_launch(void* const* d_in, const int* in_sizes, int n_in,
                              void* d_out, int out_size, void* d_ws, size_t ws_size,
                              hipStream_t stream) {
    const float* x     = (const float*)d_in[0];
    const int*   eidx  = (const int*)d_in[1];
    const float* W_in  = (const float*)d_in[2];
    const float* b_in  = (const float*)d_in[3];
    const float* W_g   = (const float*)d_in[4];
    const float* b_g   = (const float*)d_in[5];
    const float* W_out = (const float*)d_in[6];
    const float* b_out = (const float*)d_in[7];
    float* out = (float*)d_out;

    const int N = in_sizes[0] / IN_DIM;   // 100000 (divisible by 4)
    const int E = in_sizes[1] / 2;        // 1600000

    // chunks: multiples of 4
    const int chunk  = (((E + MCH  - 1) / MCH ) + 3) & ~3;
    const int chunkA = (((E + MCH2 - 1) / MCH2) + 3) & ~3;

    // ws layout: region0 = max(partf 33.6MB, partA 8.4MB) | dinv[N] | zs[N] | Wt[8192 bf16]
    const size_t partElems0 = (size_t)NGC * MCH * WIN;      // binC floats
    const size_t partElemsA = (size_t)MCH2 * AWORDS;        // binA u32 words
    const size_t partElems = partElems0 > partElemsA ? partElems0 : partElemsA;
    unsigned* partA = (unsigned*)d_ws;    // consumed by k_dense before binC overwrites
    float*    partf = (float*)d_ws;
    float*    dinv  = (float*)d_ws + partElems;
    float*    zs    = dinv + N;
    unsigned short* Wt = (unsigned short*)(zs + N);

    const int nG = (N + DNODES - 1) / DNODES;   // 1563 dense blocks
    k_binA<<<MCH2 + PREP_BLOCKS, SCAN_TPB, 0, stream>>>(eidx + E, partA, W_in, Wt, E, chunkA);
    k_dense<<<nG, 256, 0, stream>>>(x, Wt, b_in, W_g, W_out, partA, dinv, zs, N);
    k_binC<<<NGC * MCH, SCAN_TPB, 0, stream>>>(eidx, zs, partf, E, chunk);
    k_redFinal<<<((N + 3) / 4 + 255) / 256, 256, 0, stream>>>(partf, dinv, zs, b_g, W_out, b_out, out, N);
}